// Round 7
// baseline (303.770 us; speedup 1.0000x reference)
//
#include <hip/hip_runtime.h>

// DNNF fused pipeline for MI355X (gfx950). R7: 3-stage ring-buffered K-loop,
// 1 block/CU (120 KB LDS), prefetch distance 2 (~2500 cyc >> HBM latency).
// Per iter: [lgkm(0)+barrier release] -> issue DMA(k+2) -> vmcnt(20)+barrier
// (DMA(k) landed; k+1,k+2 in flight) -> ds_read + 48 MFMA per wave.
// Keeps R5 grid swizzle (x=m, 64%8==0 -> XCD-pinned A/form_sum) and R5's
// conflict-free epilogue.

#define BATCH 8192
#define IDIM 512
#define NFORM 256
#define NLIT 10752
#define WT_ROWS 11136  // NLIT + 256 mu + 128 zero pad; /192 = 58 tiles

#define BM 128
#define BN 192
#define BK 64
#define BUFB 40960  // one stage: A 16384 B + B 24576 B
#define SLITP 196   // slit row stride (floats)

typedef __bf16 bf16x8 __attribute__((ext_vector_type(8)));
typedef float f32x4 __attribute__((ext_vector_type(4)));
typedef unsigned short u16;
typedef unsigned int u32;

__device__ __forceinline__ u16 f2bf(float f) {
  u32 u = __float_as_uint(f);
  u = (u + 0x7fffu + ((u >> 16) & 1u)) >> 16;  // RNE
  return (u16)u;
}

__device__ __forceinline__ float fast_tanh(float x) {
  float e = __expf(2.0f * x);
  return 1.0f - 2.0f * __builtin_amdgcn_rcpf(e + 1.0f);
}

__device__ __forceinline__ void async_cp16(const void* g, void* l) {
  __builtin_amdgcn_global_load_lds(
      (const u32 __attribute__((address_space(1)))*)g,
      (u32 __attribute__((address_space(3)))*)l, 16, 0, 0);
}

// ---------------- fused prep (one dispatch) ----------------

#define PREPX_BLKS 2048
#define PREPW_BLKS 1344  // 168 l-tiles x 8 k-tiles

__global__ __launch_bounds__(256) void prep_all(
    const float* __restrict__ x, const float* __restrict__ W,
    const float* __restrict__ M, const float* __restrict__ mu,
    u16* __restrict__ xb, u16* __restrict__ wt, float* __restrict__ xsq,
    float* __restrict__ musq, float* __restrict__ form_sum) {
  __shared__ float lds[64 * 65];  // 16.6 KB; also reused as red[256]
  const int blk = blockIdx.x, tid = threadIdx.x;

  if (blk < PREPX_BLKS) {
    ((uint4*)form_sum)[blk * 256 + tid] = make_uint4(0, 0, 0, 0);
    int wave = tid >> 6, lane = tid & 63;
    int row = blk * 4 + wave;
    const float4* px = (const float4*)(x + (size_t)row * IDIM);
    float4 a = px[lane * 2], b = px[lane * 2 + 1];
    uint4 pk;
    pk.x = (u32)f2bf(a.x) | ((u32)f2bf(a.y) << 16);
    pk.y = (u32)f2bf(a.z) | ((u32)f2bf(a.w) << 16);
    pk.z = (u32)f2bf(b.x) | ((u32)f2bf(b.y) << 16);
    pk.w = (u32)f2bf(b.z) | ((u32)f2bf(b.w) << 16);
    ((uint4*)(xb + (size_t)row * IDIM))[lane] = pk;
    float s = a.x * a.x + a.y * a.y + a.z * a.z + a.w * a.w +
              b.x * b.x + b.y * b.y + b.z * b.z + b.w * b.w;
#pragma unroll
    for (int o = 32; o > 0; o >>= 1) s += __shfl_down(s, o);
    if (lane == 0) xsq[row] = s;
  } else if (blk < PREPX_BLKS + PREPW_BLKS) {
    int b = blk - PREPX_BLKS;
    int l0 = (b % 168) * 64, k0 = (b / 168) * 64;
#pragma unroll
    for (int j = 0; j < 4; ++j) {
      int idx = tid + j * 256;
      int kk = idx >> 4, l4 = idx & 15;
      size_t g = (size_t)(k0 + kk) * NLIT + l0 + l4 * 4;
      float4 w4 = *(const float4*)(W + g);
      float4 m4 = *(const float4*)(M + g);
      lds[kk * 65 + l4 * 4 + 0] = w4.x * m4.x;
      lds[kk * 65 + l4 * 4 + 1] = w4.y * m4.y;
      lds[kk * 65 + l4 * 4 + 2] = w4.z * m4.z;
      lds[kk * 65 + l4 * 4 + 3] = w4.w * m4.w;
    }
    __syncthreads();
    int l = tid >> 2, kq = tid & 3;
    u32 pk[8];
#pragma unroll
    for (int t = 0; t < 8; ++t) {
      u16 lo = f2bf(lds[(kq * 16 + 2 * t) * 65 + l]);
      u16 hi = f2bf(lds[(kq * 16 + 2 * t + 1) * 65 + l]);
      pk[t] = (u32)lo | ((u32)hi << 16);
    }
    u32* dst = (u32*)(wt + (size_t)(l0 + l) * IDIM + k0 + kq * 16);
    ((uint4*)dst)[0] = make_uint4(pk[0], pk[1], pk[2], pk[3]);
    ((uint4*)dst)[1] = make_uint4(pk[4], pk[5], pk[6], pk[7]);
  } else {
    int b = blk - PREPX_BLKS - PREPW_BLKS;
    if (b < 256) {
      float s = 0.f;
#pragma unroll
      for (int j = tid; j < IDIM; j += 256) {
        float v = mu[(size_t)b * IDIM + j];
        wt[(size_t)(NLIT + b) * IDIM + j] = f2bf(v);
        s += v * v;
      }
      float* red = lds;
      red[tid] = s;
      __syncthreads();
      for (int sh = 128; sh > 0; sh >>= 1) {
        if (tid < sh) red[tid] += red[tid + sh];
        __syncthreads();
      }
      if (tid == 0) musq[b] = red[0];
    } else {
      int row = NLIT + 256 + (b - 256);  // 11008..11135
      for (int j = tid; j < IDIM; j += 256) wt[(size_t)row * IDIM + j] = 0;
    }
  }
}

// ---------------- main fused GEMM (3-stage ring) ----------------

__global__ __launch_bounds__(256, 1) void dnnf_gemm(
    const u16* __restrict__ xb, const u16* __restrict__ wt,
    const float* __restrict__ bias, float* __restrict__ form_sum,
    float* __restrict__ dotbuf) {
  __shared__ __align__(16) char smraw[3 * BUFB];  // 122880 B -> 1 block/CU
  float* slit = (float*)smraw;                    // epilogue view 64 x SLITP

  const int tid = threadIdx.x;
  const int wave = tid >> 6, lane = tid & 63;
  const int wm = wave & 1, wn = wave >> 1;
  // grid: x = m (64, %8==0 -> XCD-pinned m-tiles), y = n (58)
  const int m0 = blockIdx.x * BM, n0 = blockIdx.y * BN;
  const int q = lane >> 4, cn = lane & 15;

  // staging: chunk c = tid + i*256, r = c>>3, kg = (c&7) ^ (r&7)
  const int kg8 = ((tid & 7) ^ ((tid >> 3) & 7)) * 8;
  const u16* pa = xb + (size_t)(m0 + (tid >> 3)) * IDIM + kg8;
  const u16* pb = wt + (size_t)(n0 + (tid >> 3)) * IDIM + kg8;
  const int dA = tid * 16;          // + i*4096, i<4
  const int dB = 16384 + tid * 16;  // + i*4096, i<6

  const int kg0_16 = ((q ^ (cn & 7)) << 4);
  int offA[4], offB[6];
#pragma unroll
  for (int mf = 0; mf < 4; ++mf)
    offA[mf] = (wm * 64 + mf * 16 + cn) * 128 + kg0_16;
#pragma unroll
  for (int nf = 0; nf < 6; ++nf)
    offB[nf] = 16384 + (wn * 96 + nf * 16 + cn) * 128 + kg0_16;

  f32x4 acc[4][6];
#pragma unroll
  for (int a = 0; a < 4; ++a)
#pragma unroll
    for (int b = 0; b < 6; ++b) acc[a][b] = (f32x4){0.f, 0.f, 0.f, 0.f};

  // prologue: tiles 0,1 -> stages 0,1
#pragma unroll
  for (int s = 0; s < 2; ++s) {
    char* buf = smraw + s * BUFB;
#pragma unroll
    for (int i = 0; i < 4; ++i)
      async_cp16(pa + (size_t)i * 32 * IDIM, buf + dA + i * 4096);
#pragma unroll
    for (int i = 0; i < 6; ++i)
      async_cp16(pb + (size_t)i * 32 * IDIM, buf + dB + i * 4096);
    pa += BK;
    pb += BK;
  }

#pragma unroll
  for (int kt = 0; kt < 8; ++kt) {
    const char* bufc = smraw + (kt % 3) * BUFB;
    if (kt > 0) {
      // release stage (kt+2)%3: prior-iter ds_reads must have sampled it
      asm volatile("s_waitcnt lgkmcnt(0)\n\ts_barrier" ::: "memory");
    }
    if (kt < 6) {
      char* bufn = smraw + ((kt + 2) % 3) * BUFB;
#pragma unroll
      for (int i = 0; i < 4; ++i)
        async_cp16(pa + (size_t)i * 32 * IDIM, bufn + dA + i * 4096);
#pragma unroll
      for (int i = 0; i < 6; ++i)
        async_cp16(pb + (size_t)i * 32 * IDIM, bufn + dB + i * 4096);
      pa += BK;
      pb += BK;
      // retire stage kt (10 oldest of 30); kt+1, kt+2 stay in flight
      asm volatile("s_waitcnt vmcnt(20)\n\ts_barrier" ::: "memory");
    } else if (kt == 6) {
      asm volatile("s_waitcnt vmcnt(10)\n\ts_barrier" ::: "memory");
    } else {
      asm volatile("s_waitcnt vmcnt(0)\n\ts_barrier" ::: "memory");
    }
#pragma unroll
    for (int ks = 0; ks < 2; ++ks) {
      const int x64 = ks ? 64 : 0;
      bf16x8 af[4], bfr[6];
#pragma unroll
      for (int mf = 0; mf < 4; ++mf)
        af[mf] = *(const bf16x8*)(bufc + (offA[mf] ^ x64));
#pragma unroll
      for (int nf = 0; nf < 6; ++nf)
        bfr[nf] = *(const bf16x8*)(bufc + (offB[nf] ^ x64));
#pragma unroll
      for (int mf = 0; mf < 4; ++mf)
#pragma unroll
        for (int nf = 0; nf < 6; ++nf)
          acc[mf][nf] = __builtin_amdgcn_mfma_f32_16x16x32_bf16(
              af[mf], bfr[nf], acc[mf][nf], 0, 0, 0);
    }
  }
  __syncthreads();  // full drain before LDS reuse as slit

  if (n0 < NLIT) {
    float bv[6];
#pragma unroll
    for (int nf = 0; nf < 6; ++nf) bv[nf] = bias[n0 + wn * 96 + nf * 16 + cn];

    // two phases of 64 rows, one 64 x SLITP slit tile (50 KB)
#pragma unroll
    for (int ph = 0; ph < 2; ++ph) {
      if (ph) __syncthreads();  // phase-0 reads done before overwrite
      if (wm == ph) {
#pragma unroll
        for (int nf = 0; nf < 6; ++nf) {
          int col = wn * 96 + nf * 16 + cn;
#pragma unroll
          for (int mf = 0; mf < 4; ++mf)
#pragma unroll
            for (int reg = 0; reg < 4; ++reg) {
              int lr = mf * 16 + q * 4 + reg;
              slit[lr * SLITP + col] = fast_tanh(acc[mf][nf][reg] + bv[nf]);
            }
        }
      }
      __syncthreads();

      int r = tid >> 2, sub = tid & 3;  // 64 rows x 4 threads (48 lits each)
      const float* lrow = slit + r * SLITP + sub * 48;
      int c0 = ((n0 + sub * 48) / 12) * 3;
      size_t grow = (size_t)(m0 + ph * 64 + r) * NFORM;
      float run = 0.f;
      int fprev = -1;
#pragma unroll
      for (int tr = 0; tr < 4; ++tr) {
        const float* p = lrow + tr * 12;
        float s2 = p[0] + p[1];
        float s4 = p[2] + p[3] + p[4] + p[5];
        float s6 = p[6] + p[7] + p[8] + p[9] + p[10] + p[11];
        float v = fast_tanh(s2 - 0.5f) + fast_tanh(s4 - 2.5f) +
                  fast_tanh(s6 - 4.5f);
        int c = c0 + tr * 3;
        int f = (c < 384)    ? (c / 6)
                : (c < 960)  ? 64 + (c - 384) / 9
                : (c < 1728) ? 128 + (c - 960) / 12
                             : 192 + (c - 1728) / 15;
        if (f != fprev) {
          if (fprev >= 0) atomicAdd(form_sum + grow + fprev, run);
          fprev = f;
          run = 0.f;
        }
        run += v;
      }
      atomicAdd(form_sum + grow + fprev, run);
    }
  } else {
    // mu tiles: store raw x.mu dots
#pragma unroll
    for (int nf = 0; nf < 6; ++nf) {
      int col = n0 - NLIT + wn * 96 + nf * 16 + cn;
      if (col < NFORM) {
#pragma unroll
        for (int mf = 0; mf < 4; ++mf)
#pragma unroll
          for (int reg = 0; reg < 4; ++reg) {
            int row = wm * 64 + mf * 16 + q * 4 + reg;
            dotbuf[(size_t)(m0 + row) * NFORM + col] = acc[mf][nf][reg];
          }
      }
    }
  }
}

// ---------------- finale: RBF softmax * dnnf (wave-per-row) ----------------

__global__ __launch_bounds__(256) void finale(
    const float* __restrict__ form_sum, const float* __restrict__ dotbuf,
    const float* __restrict__ xsq, const float* __restrict__ musq,
    const float* __restrict__ sigma, float* __restrict__ out) {
  int wave = threadIdx.x >> 6, lane = threadIdx.x & 63;
  int r = blockIdx.x * 4 + wave;
  size_t base = (size_t)r * NFORM;
  float xs = xsq[r];
  float e[4], s = 0.f;
#pragma unroll
  for (int j = 0; j < 4; ++j) {
    int f = j * 64 + lane;
    float sq = xs - 2.0f * dotbuf[base + f] + musq[f];
    float sg = sigma[f];
    float p = __expf(-0.5f * sq / (sg * sg));
    e[j] = __expf(2.0f * p);  // TEMPERATURE=2; values in [1, e^2]
    s += e[j];
  }
#pragma unroll
  for (int o = 32; o > 0; o >>= 1) s += __shfl_xor(s, o);
  float inv = __builtin_amdgcn_rcpf(s);
#pragma unroll
  for (int j = 0; j < 4; ++j) {
    int f = j * 64 + lane;
    float dn = fast_tanh(form_sum[base + f] + (float)(6 + 3 * j) - 1.5f);
    out[base + f] = dn * e[j] * inv;
  }
}

// ---------------- launch ----------------

extern "C" void kernel_launch(void* const* d_in, const int* in_sizes, int n_in,
                              void* d_out, int out_size, void* d_ws,
                              size_t ws_size, hipStream_t stream) {
  const float* x = (const float*)d_in[0];
  const float* W = (const float*)d_in[1];
  const float* M = (const float*)d_in[2];
  const float* bias = (const float*)d_in[3];
  const float* mu = (const float*)d_in[4];
  const float* sigma = (const float*)d_in[5];
  float* out = (float*)d_out;

  float* form_sum = (float*)d_ws;                       // 8 MB
  float* dotbuf = form_sum + (size_t)BATCH * NFORM;     // 8 MB
  u16* xb = (u16*)(dotbuf + (size_t)BATCH * NFORM);     // 8 MB
  u16* wt = xb + (size_t)BATCH * IDIM;                  // 11.4 MB
  float* xsq = (float*)(wt + (size_t)WT_ROWS * IDIM);   // 32 KB
  float* musq = xsq + BATCH;                            // 1 KB

  prep_all<<<PREPX_BLKS + PREPW_BLKS + 384, 256, 0, stream>>>(
      x, W, M, mu, xb, wt, xsq, musq, form_sum);
  // grid: x = m (64, multiple of 8 -> XCD-pinned m-tiles), y = n (58)
  dnnf_gemm<<<dim3(BATCH / BM, WT_ROWS / BN), 256, 0, stream>>>(xb, wt, bias,
                                                                form_sum, dotbuf);
  finale<<<BATCH / 4, 256, 0, stream>>>(form_sum, dotbuf, xsq, musq, sigma, out);
}

// Round 8
// 245.806 us; speedup vs baseline: 1.2358x; 1.2358x over previous
//
#include <hip/hip_runtime.h>

// DNNF fused pipeline for MI355X (gfx950). R8: DMA-concurrency fix.
// K-loop = BK=32, 3-stage ring (3x20 KB = 60 KB LDS) at 2 blocks/CU:
// steady-state outstanding DMA = 2 stages x 20 KB x 2 blocks = 80 KB/CU
// (2x R4) while keeping 8 waves/CU. Cross-round audit showed the staging
// path is latency*concurrency bound (achieved DMA rate tracks blocks/CU:
// R1 9.8 TB/s @3blk > R4 8.4 @2 > R7 5.8 @1), so raise in-flight bytes
// at constant occupancy. Keep R5 grid swizzle + conflict-free epilogue.

#define BATCH 8192
#define IDIM 512
#define NFORM 256
#define NLIT 10752
#define WT_ROWS 11136  // NLIT + 256 mu + 128 zero pad; /192 = 58 tiles

#define BM 128
#define BN 192
#define BK 32
#define STAGEB 20480  // (128 + 192) * 32 * 2 B
#define SLITP 196     // slit row stride (floats)

typedef __bf16 bf16x8 __attribute__((ext_vector_type(8)));
typedef float f32x4 __attribute__((ext_vector_type(4)));
typedef unsigned short u16;
typedef unsigned int u32;

__device__ __forceinline__ u16 f2bf(float f) {
  u32 u = __float_as_uint(f);
  u = (u + 0x7fffu + ((u >> 16) & 1u)) >> 16;  // RNE
  return (u16)u;
}

__device__ __forceinline__ float fast_tanh(float x) {
  float e = __expf(2.0f * x);
  return 1.0f - 2.0f * __builtin_amdgcn_rcpf(e + 1.0f);
}

__device__ __forceinline__ void async_cp16(const void* g, void* l) {
  __builtin_amdgcn_global_load_lds(
      (const u32 __attribute__((address_space(1)))*)g,
      (u32 __attribute__((address_space(3)))*)l, 16, 0, 0);
}

// ---------------- fused prep (one dispatch) ----------------

#define PREPX_BLKS 2048
#define PREPW_BLKS 1344  // 168 l-tiles x 8 k-tiles

__global__ __launch_bounds__(256) void prep_all(
    const float* __restrict__ x, const float* __restrict__ W,
    const float* __restrict__ M, const float* __restrict__ mu,
    u16* __restrict__ xb, u16* __restrict__ wt, float* __restrict__ xsq,
    float* __restrict__ musq, float* __restrict__ form_sum) {
  __shared__ float lds[64 * 65];  // 16.6 KB; also reused as red[256]
  const int blk = blockIdx.x, tid = threadIdx.x;

  if (blk < PREPX_BLKS) {
    ((uint4*)form_sum)[blk * 256 + tid] = make_uint4(0, 0, 0, 0);
    int wave = tid >> 6, lane = tid & 63;
    int row = blk * 4 + wave;
    const float4* px = (const float4*)(x + (size_t)row * IDIM);
    float4 a = px[lane * 2], b = px[lane * 2 + 1];
    uint4 pk;
    pk.x = (u32)f2bf(a.x) | ((u32)f2bf(a.y) << 16);
    pk.y = (u32)f2bf(a.z) | ((u32)f2bf(a.w) << 16);
    pk.z = (u32)f2bf(b.x) | ((u32)f2bf(b.y) << 16);
    pk.w = (u32)f2bf(b.z) | ((u32)f2bf(b.w) << 16);
    ((uint4*)(xb + (size_t)row * IDIM))[lane] = pk;
    float s = a.x * a.x + a.y * a.y + a.z * a.z + a.w * a.w +
              b.x * b.x + b.y * b.y + b.z * b.z + b.w * b.w;
#pragma unroll
    for (int o = 32; o > 0; o >>= 1) s += __shfl_down(s, o);
    if (lane == 0) xsq[row] = s;
  } else if (blk < PREPX_BLKS + PREPW_BLKS) {
    int b = blk - PREPX_BLKS;
    int l0 = (b % 168) * 64, k0 = (b / 168) * 64;
#pragma unroll
    for (int j = 0; j < 4; ++j) {
      int idx = tid + j * 256;
      int kk = idx >> 4, l4 = idx & 15;
      size_t g = (size_t)(k0 + kk) * NLIT + l0 + l4 * 4;
      float4 w4 = *(const float4*)(W + g);
      float4 m4 = *(const float4*)(M + g);
      lds[kk * 65 + l4 * 4 + 0] = w4.x * m4.x;
      lds[kk * 65 + l4 * 4 + 1] = w4.y * m4.y;
      lds[kk * 65 + l4 * 4 + 2] = w4.z * m4.z;
      lds[kk * 65 + l4 * 4 + 3] = w4.w * m4.w;
    }
    __syncthreads();
    int l = tid >> 2, kq = tid & 3;
    u32 pk[8];
#pragma unroll
    for (int t = 0; t < 8; ++t) {
      u16 lo = f2bf(lds[(kq * 16 + 2 * t) * 65 + l]);
      u16 hi = f2bf(lds[(kq * 16 + 2 * t + 1) * 65 + l]);
      pk[t] = (u32)lo | ((u32)hi << 16);
    }
    u32* dst = (u32*)(wt + (size_t)(l0 + l) * IDIM + k0 + kq * 16);
    ((uint4*)dst)[0] = make_uint4(pk[0], pk[1], pk[2], pk[3]);
    ((uint4*)dst)[1] = make_uint4(pk[4], pk[5], pk[6], pk[7]);
  } else {
    int b = blk - PREPX_BLKS - PREPW_BLKS;
    if (b < 256) {
      float s = 0.f;
#pragma unroll
      for (int j = tid; j < IDIM; j += 256) {
        float v = mu[(size_t)b * IDIM + j];
        wt[(size_t)(NLIT + b) * IDIM + j] = f2bf(v);
        s += v * v;
      }
      float* red = lds;
      red[tid] = s;
      __syncthreads();
      for (int sh = 128; sh > 0; sh >>= 1) {
        if (tid < sh) red[tid] += red[tid + sh];
        __syncthreads();
      }
      if (tid == 0) musq[b] = red[0];
    } else {
      int row = NLIT + 256 + (b - 256);  // 11008..11135
      for (int j = tid; j < IDIM; j += 256) wt[(size_t)row * IDIM + j] = 0;
    }
  }
}

// ---------------- main fused GEMM (BK=32, 3-stage ring) ----------------
// Stage layout: A 128 rows x 64 B, then B 192 rows x 64 B. LDS dest is the
// plain chunk address (base + c*16, lane-contiguous); the XOR swizzle
// kg_src = (c&3) ^ (r&3) ^ ((r>>2)&3) is applied on the GLOBAL source side,
// so ds_read at phys slot q^f(row) finds k-group q. 2-way banks max.
// Per iter kt: [release stage kt-1: lgkm(0)+barrier] -> issue stage kt+2
// (5 DMA) -> vmcnt(10)+barrier (stage kt landed, kt+1/kt+2 in flight) ->
// 10 ds_read_b128 + 24 MFMA.

__global__ __launch_bounds__(256, 2) void dnnf_gemm(
    const u16* __restrict__ xb, const u16* __restrict__ wt,
    const float* __restrict__ bias, float* __restrict__ form_sum,
    float* __restrict__ dotbuf) {
  __shared__ __align__(16) char smraw[3 * STAGEB];  // 61440 B -> 2 blocks/CU
  float* slit = (float*)smraw;                      // epilogue 64 x SLITP

  const int tid = threadIdx.x;
  const int wave = tid >> 6, lane = tid & 63;
  const int wm = wave & 1, wn = wave >> 1;
  // grid: x = m (64, %8==0 -> XCD-pinned m-tiles), y = n (58)
  const int m0 = blockIdx.x * BM, n0 = blockIdx.y * BN;
  const int q = lane >> 4, cn = lane & 15;

  // staging sources: chunk c = tid + i*256; i<2 -> A (rows 0..127),
  // i>=2 -> B (rows 0..191). Source k-group XOR-swizzled.
  const u16* sp[5];
  int dofs[5];
#pragma unroll
  for (int i = 0; i < 5; ++i) {
    int c = tid + i * 256;
    dofs[i] = c * 16;
    if (i < 2) {
      int r = c >> 2;
      int kg = (c & 3) ^ (r & 3) ^ ((r >> 2) & 3);
      sp[i] = xb + (size_t)(m0 + r) * IDIM + kg * 8;
    } else {
      int r = (c - 512) >> 2;
      int kg = (c & 3) ^ (r & 3) ^ ((r >> 2) & 3);
      sp[i] = wt + (size_t)(n0 + r) * IDIM + kg * 8;
    }
  }

  // ds_read offsets (constant over loop; add stage base each iter)
  int offA[4], offB[6];
#pragma unroll
  for (int mf = 0; mf < 4; ++mf) {
    int row = wm * 64 + mf * 16 + cn;
    int f = (row & 3) ^ ((row >> 2) & 3);
    offA[mf] = row * 64 + ((q ^ f) << 4);
  }
#pragma unroll
  for (int nf = 0; nf < 6; ++nf) {
    int row = wn * 96 + nf * 16 + cn;
    int f = (row & 3) ^ ((row >> 2) & 3);
    offB[nf] = 8192 + row * 64 + ((q ^ f) << 4);
  }

  f32x4 acc[4][6];
#pragma unroll
  for (int a = 0; a < 4; ++a)
#pragma unroll
    for (int b = 0; b < 6; ++b) acc[a][b] = (f32x4){0.f, 0.f, 0.f, 0.f};

  // prologue: stages 0,1
#pragma unroll
  for (int s = 0; s < 2; ++s)
#pragma unroll
    for (int i = 0; i < 5; ++i)
      async_cp16(sp[i] + s * BK, smraw + s * STAGEB + dofs[i]);

#pragma unroll
  for (int kt = 0; kt < 16; ++kt) {
    const char* bufc = smraw + (kt % 3) * STAGEB;
    if (kt > 0) {
      // stage kt-1 fully sampled before its buffer is re-DMA'd
      asm volatile("s_waitcnt lgkmcnt(0)\n\ts_barrier" ::: "memory");
    }
    if (kt < 14) {
      char* bufn = smraw + ((kt + 2) % 3) * STAGEB;
#pragma unroll
      for (int i = 0; i < 5; ++i)
        async_cp16(sp[i] + (kt + 2) * BK, bufn + dofs[i]);
      // retire stage kt (5 oldest of 15); kt+1, kt+2 stay in flight
      asm volatile("s_waitcnt vmcnt(10)\n\ts_barrier" ::: "memory");
    } else if (kt == 14) {
      asm volatile("s_waitcnt vmcnt(5)\n\ts_barrier" ::: "memory");
    } else {
      asm volatile("s_waitcnt vmcnt(0)\n\ts_barrier" ::: "memory");
    }
    bf16x8 af[4], bfr[6];
#pragma unroll
    for (int mf = 0; mf < 4; ++mf)
      af[mf] = *(const bf16x8*)(bufc + offA[mf]);
#pragma unroll
    for (int nf = 0; nf < 6; ++nf)
      bfr[nf] = *(const bf16x8*)(bufc + offB[nf]);
#pragma unroll
    for (int mf = 0; mf < 4; ++mf)
#pragma unroll
      for (int nf = 0; nf < 6; ++nf)
        acc[mf][nf] = __builtin_amdgcn_mfma_f32_16x16x32_bf16(
            af[mf], bfr[nf], acc[mf][nf], 0, 0, 0);
  }
  __syncthreads();  // full drain before LDS reuse as slit

  if (n0 < NLIT) {
    float bv[6];
#pragma unroll
    for (int nf = 0; nf < 6; ++nf) bv[nf] = bias[n0 + wn * 96 + nf * 16 + cn];

    // two phases of 64 rows, one 64 x SLITP slit tile (50 KB)
#pragma unroll
    for (int ph = 0; ph < 2; ++ph) {
      if (ph) __syncthreads();  // phase-0 reads done before overwrite
      if (wm == ph) {
#pragma unroll
        for (int nf = 0; nf < 6; ++nf) {
          int col = wn * 96 + nf * 16 + cn;
#pragma unroll
          for (int mf = 0; mf < 4; ++mf)
#pragma unroll
            for (int reg = 0; reg < 4; ++reg) {
              int lr = mf * 16 + q * 4 + reg;
              slit[lr * SLITP + col] = fast_tanh(acc[mf][nf][reg] + bv[nf]);
            }
        }
      }
      __syncthreads();

      int r = tid >> 2, sub = tid & 3;  // 64 rows x 4 threads (48 lits each)
      const float* lrow = slit + r * SLITP + sub * 48;
      int c0 = ((n0 + sub * 48) / 12) * 3;
      size_t grow = (size_t)(m0 + ph * 64 + r) * NFORM;
      float run = 0.f;
      int fprev = -1;
#pragma unroll
      for (int tr = 0; tr < 4; ++tr) {
        const float* p = lrow + tr * 12;
        float s2 = p[0] + p[1];
        float s4 = p[2] + p[3] + p[4] + p[5];
        float s6 = p[6] + p[7] + p[8] + p[9] + p[10] + p[11];
        float v = fast_tanh(s2 - 0.5f) + fast_tanh(s4 - 2.5f) +
                  fast_tanh(s6 - 4.5f);
        int c = c0 + tr * 3;
        int f = (c < 384)    ? (c / 6)
                : (c < 960)  ? 64 + (c - 384) / 9
                : (c < 1728) ? 128 + (c - 960) / 12
                             : 192 + (c - 1728) / 15;
        if (f != fprev) {
          if (fprev >= 0) atomicAdd(form_sum + grow + fprev, run);
          fprev = f;
          run = 0.f;
        }
        run += v;
      }
      atomicAdd(form_sum + grow + fprev, run);
    }
  } else {
    // mu tiles: store raw x.mu dots
#pragma unroll
    for (int nf = 0; nf < 6; ++nf) {
      int col = n0 - NLIT + wn * 96 + nf * 16 + cn;
      if (col < NFORM) {
#pragma unroll
        for (int mf = 0; mf < 4; ++mf)
#pragma unroll
          for (int reg = 0; reg < 4; ++reg) {
            int row = wm * 64 + mf * 16 + q * 4 + reg;
            dotbuf[(size_t)(m0 + row) * NFORM + col] = acc[mf][nf][reg];
          }
      }
    }
  }
}

// ---------------- finale: RBF softmax * dnnf (wave-per-row) ----------------

__global__ __launch_bounds__(256) void finale(
    const float* __restrict__ form_sum, const float* __restrict__ dotbuf,
    const float* __restrict__ xsq, const float* __restrict__ musq,
    const float* __restrict__ sigma, float* __restrict__ out) {
  int wave = threadIdx.x >> 6, lane = threadIdx.x & 63;
  int r = blockIdx.x * 4 + wave;
  size_t base = (size_t)r * NFORM;
  float xs = xsq[r];
  float e[4], s = 0.f;
#pragma unroll
  for (int j = 0; j < 4; ++j) {
    int f = j * 64 + lane;
    float sq = xs - 2.0f * dotbuf[base + f] + musq[f];
    float sg = sigma[f];
    float p = __expf(-0.5f * sq / (sg * sg));
    e[j] = __expf(2.0f * p);  // TEMPERATURE=2; values in [1, e^2]
    s += e[j];
  }
#pragma unroll
  for (int o = 32; o > 0; o >>= 1) s += __shfl_xor(s, o);
  float inv = __builtin_amdgcn_rcpf(s);
#pragma unroll
  for (int j = 0; j < 4; ++j) {
    int f = j * 64 + lane;
    float dn = fast_tanh(form_sum[base + f] + (float)(6 + 3 * j) - 1.5f);
    out[base + f] = dn * e[j] * inv;
  }
}

// ---------------- launch ----------------

extern "C" void kernel_launch(void* const* d_in, const int* in_sizes, int n_in,
                              void* d_out, int out_size, void* d_ws,
                              size_t ws_size, hipStream_t stream) {
  const float* x = (const float*)d_in[0];
  const float* W = (const float*)d_in[1];
  const float* M = (const float*)d_in[2];
  const float* bias = (const float*)d_in[3];
  const float* mu = (const float*)d_in[4];
  const float* sigma = (const float*)d_in[5];
  float* out = (float*)d_out;

  float* form_sum = (float*)d_ws;                       // 8 MB
  float* dotbuf = form_sum + (size_t)BATCH * NFORM;     // 8 MB
  u16* xb = (u16*)(dotbuf + (size_t)BATCH * NFORM);     // 8 MB
  u16* wt = xb + (size_t)BATCH * IDIM;                  // 11.4 MB
  float* xsq = (float*)(wt + (size_t)WT_ROWS * IDIM);   // 32 KB
  float* musq = xsq + BATCH;                            // 1 KB

  prep_all<<<PREPX_BLKS + PREPW_BLKS + 384, 256, 0, stream>>>(
      x, W, M, mu, xb, wt, xsq, musq, form_sum);
  // grid: x = m (64, multiple of 8 -> XCD-pinned m-tiles), y = n (58)
  dnnf_gemm<<<dim3(BATCH / BM, WT_ROWS / BN), 256, 0, stream>>>(xb, wt, bias,
                                                                form_sum, dotbuf);
  finale<<<BATCH / 4, 256, 0, stream>>>(form_sum, dotbuf, xsq, musq, sigma, out);
}